// Round 5
// baseline (4584.231 us; speedup 1.0000x reference)
//
#include <hip/hip_runtime.h>

// QRNN: T=512, B=32, D=1024, Q=256.
//  Phase A (prep):  build WhT/UhT fp16 [e][d] (transposed); fill hbuf ring with NaN sentinel.
//  Phase B (gemm):  wh_out = x @ Wh + b  -> written fp32 into d_out (overwritten by scan).
//  Phase C (scan):  h_t = tanh(wh_out[t] + h_{t-1} @ Uh), in-place on d_out.
//      64 WGs = 2 row-groups x 32 col-groups; 128 thr/WG (2 waves x 16 cols).
//  R6: sentinel protocol (R3's, correctness-proven) with the consumer done right:
//      * ALL loads via __hip_atomic_load (compiler-managed waitcnts; R4's raw-asm burst
//        corrupted registers between issue and hand-placed vmcnt).
//      * ONE collective round: load all 64 u64, validate all 128 words in registers,
//        retry the WHOLE block (each round = one pipelined LLC RT) until clean.
//        (R3 failed by splitting detection into 4 sequential ballot rounds.)
//      * Producer critical path ends at "4 u32 stores issued": NO drain, NO flag,
//        NO syncthreads. Publish latency = one-way store to LLC.
//      * fp32 out stores after publish (R5: keeps HBM acks off the publish path;
//        R2 measured a drain containing HBM traffic at ~1us/step).
//      8-slot ring (512KB); wave re-sentinels its own 512B of slot (t+3)&7 at step t
//      (same-address same-wave ordering guarantees sentinel-then-data; row-group skew
//      <=1 step bounds reader windows — argument validated by R3 passing).

#define TT 512
#define BB 32
#define DD 1024
#define SENT32 0x7E007E00u

typedef _Float16 f16;
typedef _Float16 f16x8 __attribute__((ext_vector_type(8)));
typedef _Float16 f16x4 __attribute__((ext_vector_type(4)));
typedef float f32x4 __attribute__((ext_vector_type(4)));
typedef unsigned int u32;
typedef unsigned long long u64;

__device__ __constant__ int   QCOMP[4][4] = {{0,1,2,3},{1,0,3,2},{2,3,0,1},{3,2,1,0}};
__device__ __constant__ float QSIGN[4][4] = {{ 1.f, 1.f, 1.f, 1.f},
                                             {-1.f, 1.f, 1.f,-1.f},
                                             {-1.f,-1.f, 1.f, 1.f},
                                             {-1.f, 1.f,-1.f, 1.f}};

__device__ __forceinline__ float qpick(int cmp, const float* a, const float* b,
                                       const float* c, const float* d, int idx) {
    const float* s = (cmp == 0) ? a : (cmp == 1) ? b : (cmp == 2) ? c : d;
    return s[idx];
}

// ---------------- Phase A -------------------------------------------------------------
__global__ void qrnn_prep(const float* __restrict__ wr, const float* __restrict__ wi,
                          const float* __restrict__ wj, const float* __restrict__ wk,
                          const float* __restrict__ ur, const float* __restrict__ ui,
                          const float* __restrict__ uj, const float* __restrict__ uk,
                          f16* __restrict__ WhT, f16* __restrict__ UhT,
                          unsigned int* __restrict__ hbuf)
{
    int bid = blockIdx.x;
    int gid = bid * 256 + threadIdx.x;
    if (bid < 4096) {                    // WhT: 1M elements, flat = e*1024 + d
        int e = gid >> 10, d = gid & 1023;
        int bc = e >> 8, j = e & 255, br = d >> 8, i = d & 255;
        float v = QSIGN[br][bc] * qpick(QCOMP[br][bc], wr, wi, wj, wk, i * 256 + j);
        WhT[gid] = (f16)v;
    } else if (bid < 8192) {             // UhT
        int g = gid - 4096 * 256;
        int e = g >> 10, d = g & 1023;
        int bc = e >> 8, j = e & 255, br = d >> 8, i = d & 255;
        float v = QSIGN[br][bc] * qpick(QCOMP[br][bc], ur, ui, uj, uk, i * 256 + j);
        UhT[g] = (f16)v;
    } else {                             // hbuf sentinel fill: 8 slots x 64KB = 32768 uint4
        int g = gid - 8192 * 256;
        if (g < 32768) {
            uint4 s = {SENT32, SENT32, SENT32, SENT32};
            ((uint4*)hbuf)[g] = s;
        }
    }
}

// ---------------- Phase B: wh_out = x @ Wh + bias ------------------------------------
__global__ __launch_bounds__(256) void qrnn_gemm(const float* __restrict__ x,
                                                 const f16* __restrict__ WhT,
                                                 const float* __restrict__ bias,
                                                 float* __restrict__ out)
{
    __shared__ f16 Ash[128][72];
    __shared__ f16 Bsh[128][72];

    const int tn = blockIdx.x, tm = blockIdx.y;
    const int tid = threadIdx.x;
    const int lane = tid & 63, w = tid >> 6;
    const int wm = (w >> 1) * 64, wn = (w & 1) * 64;
    const int m0 = tm * 128, n0 = tn * 128;
    const int l15 = lane & 15, q8 = (lane >> 4) * 8;

    f32x4 acc[4][4] = {};

    const int arow = tid >> 4;
    const int acol = (tid & 15) * 4;
    const int brow = tid >> 3;
    const int bcol = (tid & 7) * 8;

    for (int kb = 0; kb < DD; kb += 64) {
        #pragma unroll
        for (int p = 0; p < 8; ++p) {
            int rrow = p * 16 + arow;
            float4 v = *(const float4*)(x + (size_t)(m0 + rrow) * DD + kb + acol);
            f16x4 hv = {(f16)v.x, (f16)v.y, (f16)v.z, (f16)v.w};
            *(f16x4*)&Ash[rrow][acol] = hv;
        }
        #pragma unroll
        for (int p = 0; p < 4; ++p) {
            int rn = p * 32 + brow;
            f16x8 v = *(const f16x8*)(WhT + (size_t)(n0 + rn) * DD + kb + bcol);
            *(f16x8*)&Bsh[rn][bcol] = v;
        }
        __syncthreads();
        #pragma unroll
        for (int ks = 0; ks < 64; ks += 32) {
            f16x8 af[4], bf[4];
            #pragma unroll
            for (int i = 0; i < 4; ++i) af[i] = *(const f16x8*)&Ash[wm + i * 16 + l15][ks + q8];
            #pragma unroll
            for (int i = 0; i < 4; ++i) bf[i] = *(const f16x8*)&Bsh[wn + i * 16 + l15][ks + q8];
            #pragma unroll
            for (int i = 0; i < 4; ++i)
                #pragma unroll
                for (int j = 0; j < 4; ++j)
                    acc[i][j] = __builtin_amdgcn_mfma_f32_16x16x32_f16(af[i], bf[j], acc[i][j], 0, 0, 0);
        }
        __syncthreads();
    }
    const int quad = lane >> 4;
    #pragma unroll
    for (int i = 0; i < 4; ++i)
        #pragma unroll
        for (int j = 0; j < 4; ++j) {
            int col = n0 + wn + j * 16 + l15;
            float bz = bias[col];
            #pragma unroll
            for (int rr = 0; rr < 4; ++rr) {
                int row = m0 + wm + i * 16 + quad * 4 + rr;
                out[(size_t)row * DD + col] = acc[i][j][rr] + bz;
            }
        }
}

// ---------------- Phase C: sequential scan (sentinel, check-all / retry-all) ---------
__global__ __launch_bounds__(128, 1) void qrnn_scan(const f16* __restrict__ UhT,
                                                    unsigned int* __restrict__ hbuf,
                                                    float* __restrict__ out)
{
    __shared__ f16 Ush[32][1032];   // 32 cols x 1024 k, +8 pad (2-way bank alias = free)

    const int r = blockIdx.x >> 5;          // row group 0..1
    const int c = blockIdx.x & 31;          // col group 0..31
    const int tid = threadIdx.x;
    const int w = tid >> 6, lane = tid & 63;
    const int l15 = lane & 15, quad = lane >> 4, q8 = quad * 8;
    const int dcol = c * 32 + w * 16 + l15; // output feature col (D-frag n)
    const int bq = r * 16 + quad * 4;       // first output batch row (D-frag)

    // stage Uh slice -> LDS: each thread 256 halves of one row
    {
        const int nl = tid >> 2, k0 = (tid & 3) * 256;
        const f16* src = UhT + (size_t)(c * 32 + nl) * DD + k0;
        #pragma unroll
        for (int p = 0; p < 32; ++p)
            *(f16x8*)&Ush[nl][k0 + p * 8] = *(const f16x8*)(src + p * 8);
    }
    __syncthreads();   // only barrier in the kernel

    const int nloc = w * 16 + l15;          // local col for B-frag reads

    // ring geometry: 8 slots x 64KB; element idx = row*1024 + k; byte = idx*2
    char* hb = (char*)hbuf;
    const size_t a_off = ((size_t)(r * 16 + l15) * 1024 + q8) * 2;   // A[m][k], m = l15
    const size_t w_off = ((size_t)bq * 1024 + (size_t)(dcol & ~1)) * 2;

    #pragma unroll 1
    for (int t = 0; t < TT; ++t) {
        const size_t obase = (size_t)t * (BB * DD) + (size_t)bq * DD + dcol;

        // wh at loop top: consumer-local, overlapped with the data-wait below
        float wh[4];
        #pragma unroll
        for (int i = 0; i < 4; ++i) wh[i] = out[obase + (size_t)i * DD];

        f32x4 acc[4] = {};
        if (t > 0) {
            const char* ha = hb + (size_t)((t - 1) & 7) * 65536 + a_off;
            u64 A[64];   // frag u = {A[2u], A[2u+1]}; frag stride 64B, k = u*32 + q8

            // one collective round: load everything, validate everything
            #pragma unroll
            for (int u = 0; u < 32; ++u) {
                A[2 * u]     = __hip_atomic_load((const u64*)(ha + u * 64),
                                                 __ATOMIC_RELAXED, __HIP_MEMORY_SCOPE_AGENT);
                A[2 * u + 1] = __hip_atomic_load((const u64*)(ha + u * 64 + 8),
                                                 __ATOMIC_RELAXED, __HIP_MEMORY_SCOPE_AGENT);
            }
            for (;;) {
                unsigned bad = 0;
                #pragma unroll
                for (int j = 0; j < 64; ++j)
                    bad |= (unsigned)((u32)A[j] == SENT32) |
                           (unsigned)((u32)(A[j] >> 32) == SENT32);
                if (!__any((int)bad)) break;
                // retry-all: one pipelined LLC round trip, spread over 512 lines
                #pragma unroll
                for (int u = 0; u < 32; ++u) {
                    A[2 * u]     = __hip_atomic_load((const u64*)(ha + u * 64),
                                                     __ATOMIC_RELAXED, __HIP_MEMORY_SCOPE_AGENT);
                    A[2 * u + 1] = __hip_atomic_load((const u64*)(ha + u * 64 + 8),
                                                     __ATOMIC_RELAXED, __HIP_MEMORY_SCOPE_AGENT);
                }
            }

            // 32 MFMAs, 4 independent accumulator chains
            #pragma unroll
            for (int u = 0; u < 32; ++u) {
                union { u64 q[2]; f16x8 v; } uu;
                uu.q[0] = A[2 * u];
                uu.q[1] = A[2 * u + 1];
                f16x8 bf = *(const f16x8*)&Ush[nloc][u * 32 + q8];
                acc[u & 3] = __builtin_amdgcn_mfma_f32_16x16x32_f16(uu.v, bf, acc[u & 3], 0, 0, 0);
            }
        }

        // epilogue: compute h, publish ring (fire-and-forget: the END of the producer
        // critical path), then re-sentinel, then fp32 out stores (lazy HBM drain).
        float hv[4];
        #pragma unroll
        for (int i = 0; i < 4; ++i) {
            float z = (acc[0][i] + acc[1][i]) + (acc[2][i] + acc[3][i]) + wh[i];
            float e = __expf(2.0f * z);
            hv[i] = 1.0f - 2.0f * __builtin_amdgcn_rcpf(e + 1.0f);
        }

        if (t < TT - 1) {
            char* hwp = hb + (size_t)(t & 7) * 65536 + w_off;
            #pragma unroll
            for (int i = 0; i < 4; ++i) {
                f16 hh = (f16)hv[i];
                unsigned short hbits = __builtin_bit_cast(unsigned short, hh);
                int other = __shfl_xor((int)hbits, 1, 64);   // partner col (l15 ^ 1)
                if ((lane & 1) == 0) {
                    unsigned int packed = (unsigned int)hbits | ((unsigned int)other << 16);
                    __hip_atomic_store((unsigned int*)(hwp + (size_t)i * 2048), packed,
                                       __ATOMIC_RELAXED, __HIP_MEMORY_SCOPE_AGENT);
                }
            }
        }

        // re-sentinel own 512B region of slot (t+3)&7 (reused by self at t+3; same-wave
        // same-address ordering makes sentinel-then-data safe; old readers done by skew<=1).
        if (t < TT - 4 && (lane & 1) == 0) {
            char* hri = hb + (size_t)((t + 3) & 7) * 65536 + w_off;
            #pragma unroll
            for (int i = 0; i < 4; ++i)
                __hip_atomic_store((unsigned int*)(hri + (size_t)i * 2048), SENT32,
                                   __ATOMIC_RELAXED, __HIP_MEMORY_SCOPE_AGENT);
        }

        // fp32 h -> d_out, off every critical path
        #pragma unroll
        for (int i = 0; i < 4; ++i) out[obase + (size_t)i * DD] = hv[i];
    }
}

extern "C" void kernel_launch(void* const* d_in, const int* in_sizes, int n_in,
                              void* d_out, int out_size, void* d_ws, size_t ws_size,
                              hipStream_t stream)
{
    const float* x  = (const float*)d_in[0];
    const float* wr = (const float*)d_in[1];
    const float* wi = (const float*)d_in[2];
    const float* wj = (const float*)d_in[3];
    const float* wk = (const float*)d_in[4];
    const float* ur = (const float*)d_in[5];
    const float* ui = (const float*)d_in[6];
    const float* uj = (const float*)d_in[7];
    const float* uk = (const float*)d_in[8];
    const float* bias = (const float*)d_in[9];
    float* out = (float*)d_out;

    char* ws = (char*)d_ws;
    f16* WhT  = (f16*)(ws);                          // 2 MB
    f16* UhT  = (f16*)(ws + (1 << 21));              // 2 MB
    unsigned int* hbuf = (unsigned int*)(ws + (1 << 22));   // 8 x 64 KB ring

    hipLaunchKernelGGL(qrnn_prep, dim3(8320), dim3(256), 0, stream,
                       wr, wi, wj, wk, ur, ui, uj, uk, WhT, UhT, hbuf);
    hipLaunchKernelGGL(qrnn_gemm, dim3(8, 128), dim3(256), 0, stream,
                       x, WhT, bias, out);
    hipLaunchKernelGGL(qrnn_scan, dim3(64), dim3(128), 0, stream,
                       UhT, hbuf, out);
}

// Round 6
// 3199.762 us; speedup vs baseline: 1.4327x; 1.4327x over previous
//
#include <hip/hip_runtime.h>

// QRNN: T=512, B=32, D=1024, Q=256.
//  Phase A (prep):  build WhT/UhT fp16 [e][d] (transposed); zero flags.
//  Phase B (gemm):  wh_out = x @ Wh + b  -> written fp32 into d_out (overwritten by scan).
//  Phase C (scan):  h_t = tanh(wh_out[t] + h_{t-1} @ Uh), in-place on d_out.
//      64 WGs = 2 row-groups x 32 col-groups; 128 thr/WG (2 waves x 16 cols).
//  R7 = R1 (proven best, 3007us scan) with exactly two deltas:
//    * fp32 out stores AFTER the flag publish: the pre-flag vmcnt(0) drain now waits only
//      the 4 ring u32 LLC stores, not HBM store acks (R2 measured HBM-in-drain ~1us/step).
//      Own out region is never read by anyone else -> publish-irrelevant. The out stores
//      retire lazily under the next step's poll spin.
//    * s_sleep(2) backoff in the poll body: 1024 pollers hammer the flag lines; backoff
//      lets producer flag stores gain the line sooner (R5's 8x-storm variant regressed).
//  Protocol evidence: flags+barriers > per-wave flags (R5) > sentinel (R3/R6 — retry
//  reload traffic, FETCH +133..+295MB). All inter-WG traffic via coherent atomics
//  (sc0 sc1 -> LLC); no agent fences (whole-L2 buffer_inv/wbl2).

#define TT 512
#define BB 32
#define DD 1024

typedef _Float16 f16;
typedef _Float16 f16x8 __attribute__((ext_vector_type(8)));
typedef _Float16 f16x4 __attribute__((ext_vector_type(4)));
typedef float f32x4 __attribute__((ext_vector_type(4)));
typedef unsigned long long u64;

__device__ __constant__ int   QCOMP[4][4] = {{0,1,2,3},{1,0,3,2},{2,3,0,1},{3,2,1,0}};
__device__ __constant__ float QSIGN[4][4] = {{ 1.f, 1.f, 1.f, 1.f},
                                             {-1.f, 1.f, 1.f,-1.f},
                                             {-1.f,-1.f, 1.f, 1.f},
                                             {-1.f, 1.f,-1.f, 1.f}};

__device__ __forceinline__ float qpick(int cmp, const float* a, const float* b,
                                       const float* c, const float* d, int idx) {
    const float* s = (cmp == 0) ? a : (cmp == 1) ? b : (cmp == 2) ? c : d;
    return s[idx];
}

// ---------------- Phase A -------------------------------------------------------------
__global__ void qrnn_prep(const float* __restrict__ wr, const float* __restrict__ wi,
                          const float* __restrict__ wj, const float* __restrict__ wk,
                          const float* __restrict__ ur, const float* __restrict__ ui,
                          const float* __restrict__ uj, const float* __restrict__ uk,
                          f16* __restrict__ WhT, f16* __restrict__ UhT,
                          int* __restrict__ flags)
{
    int bid = blockIdx.x;
    int gid = bid * 256 + threadIdx.x;
    if (bid < 4096) {                    // WhT: 1M elements, flat = e*1024 + d
        int e = gid >> 10, d = gid & 1023;
        int bc = e >> 8, j = e & 255, br = d >> 8, i = d & 255;
        float v = QSIGN[br][bc] * qpick(QCOMP[br][bc], wr, wi, wj, wk, i * 256 + j);
        WhT[gid] = (f16)v;
    } else if (bid < 8192) {             // UhT
        int g = gid - 4096 * 256;
        int e = g >> 10, d = g & 1023;
        int bc = e >> 8, j = e & 255, br = d >> 8, i = d & 255;
        float v = QSIGN[br][bc] * qpick(QCOMP[br][bc], ur, ui, uj, uk, i * 256 + j);
        UhT[g] = (f16)v;
    } else {                             // flags: 2*512*32 = 32768 ints -> zero
        int g = gid - 8192 * 256;
        if (g < 2 * 512 * 32) flags[g] = 0;
    }
}

// ---------------- Phase B: wh_out = x @ Wh + bias ------------------------------------
__global__ __launch_bounds__(256) void qrnn_gemm(const float* __restrict__ x,
                                                 const f16* __restrict__ WhT,
                                                 const float* __restrict__ bias,
                                                 float* __restrict__ out)
{
    __shared__ f16 Ash[128][72];
    __shared__ f16 Bsh[128][72];

    const int tn = blockIdx.x, tm = blockIdx.y;
    const int tid = threadIdx.x;
    const int lane = tid & 63, w = tid >> 6;
    const int wm = (w >> 1) * 64, wn = (w & 1) * 64;
    const int m0 = tm * 128, n0 = tn * 128;
    const int l15 = lane & 15, q8 = (lane >> 4) * 8;

    f32x4 acc[4][4] = {};

    const int arow = tid >> 4;
    const int acol = (tid & 15) * 4;
    const int brow = tid >> 3;
    const int bcol = (tid & 7) * 8;

    for (int kb = 0; kb < DD; kb += 64) {
        #pragma unroll
        for (int p = 0; p < 8; ++p) {
            int rrow = p * 16 + arow;
            float4 v = *(const float4*)(x + (size_t)(m0 + rrow) * DD + kb + acol);
            f16x4 hv = {(f16)v.x, (f16)v.y, (f16)v.z, (f16)v.w};
            *(f16x4*)&Ash[rrow][acol] = hv;
        }
        #pragma unroll
        for (int p = 0; p < 4; ++p) {
            int rn = p * 32 + brow;
            f16x8 v = *(const f16x8*)(WhT + (size_t)(n0 + rn) * DD + kb + bcol);
            *(f16x8*)&Bsh[rn][bcol] = v;
        }
        __syncthreads();
        #pragma unroll
        for (int ks = 0; ks < 64; ks += 32) {
            f16x8 af[4], bf[4];
            #pragma unroll
            for (int i = 0; i < 4; ++i) af[i] = *(const f16x8*)&Ash[wm + i * 16 + l15][ks + q8];
            #pragma unroll
            for (int i = 0; i < 4; ++i) bf[i] = *(const f16x8*)&Bsh[wn + i * 16 + l15][ks + q8];
            #pragma unroll
            for (int i = 0; i < 4; ++i)
                #pragma unroll
                for (int j = 0; j < 4; ++j)
                    acc[i][j] = __builtin_amdgcn_mfma_f32_16x16x32_f16(af[i], bf[j], acc[i][j], 0, 0, 0);
        }
        __syncthreads();
    }
    const int quad = lane >> 4;
    #pragma unroll
    for (int i = 0; i < 4; ++i)
        #pragma unroll
        for (int j = 0; j < 4; ++j) {
            int col = n0 + wn + j * 16 + l15;
            float bz = bias[col];
            #pragma unroll
            for (int rr = 0; rr < 4; ++rr) {
                int row = m0 + wm + i * 16 + quad * 4 + rr;
                out[(size_t)row * DD + col] = acc[i][j][rr] + bz;
            }
        }
}

// ---------------- Phase C: sequential scan -------------------------------------------
// WG (r,c): batch rows [16r,16r+16), cols [32c,32c+32). Wave w: 16 cols.
// R1 protocol: per-(r,t) flags set by one thread per WG, polled by 32 threads; two
// barriers per step. Deltas: ring-only drain (out stores after publish), poll backoff.
__global__ __launch_bounds__(128, 1) void qrnn_scan(const f16* __restrict__ UhT,
                                                    unsigned int* __restrict__ hbuf,
                                                    int* __restrict__ flags,
                                                    float* __restrict__ out)
{
    __shared__ f16 Ush[32][1032];   // 32 cols x 1024 k, +8 pad (2-way bank alias = free)

    const int r = blockIdx.x >> 5;          // row group 0..1
    const int c = blockIdx.x & 31;          // col group 0..31
    const int tid = threadIdx.x;
    const int w = tid >> 6, lane = tid & 63;
    const int l15 = lane & 15, quad = lane >> 4, q8 = quad * 8;
    const int dcol = c * 32 + w * 16 + l15; // output feature col (D-frag n)
    const int bq = r * 16 + quad * 4;       // first output batch row (D-frag)

    // stage Uh slice -> LDS: each thread 256 halves of one row
    {
        const int nl = tid >> 2, k0 = (tid & 3) * 256;
        const f16* src = UhT + (size_t)(c * 32 + nl) * DD + k0;
        #pragma unroll
        for (int p = 0; p < 32; ++p)
            *(f16x8*)&Ush[nl][k0 + p * 8] = *(const f16x8*)(src + p * 8);
    }
    __syncthreads();

    const int nloc = w * 16 + l15;          // local col for B-frag reads

    // comm buffer geometry (fp16 elements addressed via u32/u64)
    // element idx = row*1024 + k ; byte = idx*2 ; buffers at parity*65536 bytes
    char* hb = (char*)hbuf;
    const char* harow = hb + (size_t)((r * 16 + l15) * 1024 + q8) * 2;  // A[m][k] m=l15
    char* hwrow = hb + (size_t)(bq * 1024 + (dcol & ~1)) * 2;           // packed u32 store base

    #pragma unroll 1
    for (int t = 0; t < TT; ++t) {
        const size_t obase = (size_t)t * (BB * DD) + (size_t)bq * DD + dcol;

        // wh at loop top: consumer-local latency, overlapped with the flag poll below
        float wh[4];
        #pragma unroll
        for (int i = 0; i < 4; ++i) wh[i] = out[obase + (size_t)i * DD];

        f32x4 acc[4] = {};
        if (t > 0) {
            if (tid < 32) {
                int* fp = flags + ((r << 9) + (t - 1)) * 32 + tid;
                while (__hip_atomic_load(fp, __ATOMIC_RELAXED, __HIP_MEMORY_SCOPE_AGENT) == 0) {
                    __builtin_amdgcn_s_sleep(2);   // backoff: reduce flag-line read storm
                }
            }
            __syncthreads();   // drains poll loads; broadcasts "all flags set"

            const char* ha = harow + ((t - 1) & 1) * 65536;
            #pragma unroll
            for (int u = 0; u < 32; ++u) {
                union { u64 q[2]; f16x8 v; } uu;
                uu.q[0] = __hip_atomic_load((const u64*)(ha + u * 64),
                                            __ATOMIC_RELAXED, __HIP_MEMORY_SCOPE_AGENT);
                uu.q[1] = __hip_atomic_load((const u64*)(ha + u * 64 + 8),
                                            __ATOMIC_RELAXED, __HIP_MEMORY_SCOPE_AGENT);
                f16x8 bf = *(const f16x8*)&Ush[nloc][u * 32 + q8];
                acc[u & 3] = __builtin_amdgcn_mfma_f32_16x16x32_f16(uu.v, bf, acc[u & 3], 0, 0, 0);
            }
        }

        // epilogue: compute h; publish ring, drain (ring LLC stores ONLY), barrier, flag.
        float hv[4];
        #pragma unroll
        for (int i = 0; i < 4; ++i) {
            float z = (acc[0][i] + acc[1][i]) + (acc[2][i] + acc[3][i]) + wh[i];
            float e = __expf(2.0f * z);
            hv[i] = 1.0f - 2.0f * __builtin_amdgcn_rcpf(e + 1.0f);
        }

        if (t < TT - 1) {
            char* hwp = hwrow + (t & 1) * 65536;
            #pragma unroll
            for (int i = 0; i < 4; ++i) {
                f16 hh = (f16)hv[i];
                unsigned short hbits = __builtin_bit_cast(unsigned short, hh);
                int other = __shfl_xor((int)hbits, 1, 64);   // partner col (l15 ^ 1)
                if ((lane & 1) == 0) {
                    unsigned int packed = (unsigned int)hbits | ((unsigned int)other << 16);
                    __hip_atomic_store((unsigned int*)(hwp + (size_t)i * 2048), packed,
                                       __ATOMIC_RELAXED, __HIP_MEMORY_SCOPE_AGENT);
                }
            }
            // ring-only drain: wh/data loads already waited, previous out stores retired
            // under the poll. Only the 4 ring stores are outstanding here.
            asm volatile("s_waitcnt vmcnt(0)" ::: "memory");
            __syncthreads();                                   // all waves drained
            if (tid == 0)
                __hip_atomic_store(flags + ((r << 9) + t) * 32 + c, 1,
                                   __ATOMIC_RELAXED, __HIP_MEMORY_SCOPE_AGENT);
            __builtin_amdgcn_sched_barrier(0);   // keep out stores below the publish
        }

        // fp32 h -> d_out AFTER publish: HBM acks retire lazily under the next poll.
        #pragma unroll
        for (int i = 0; i < 4; ++i) out[obase + (size_t)i * DD] = hv[i];
    }
}

extern "C" void kernel_launch(void* const* d_in, const int* in_sizes, int n_in,
                              void* d_out, int out_size, void* d_ws, size_t ws_size,
                              hipStream_t stream)
{
    const float* x  = (const float*)d_in[0];
    const float* wr = (const float*)d_in[1];
    const float* wi = (const float*)d_in[2];
    const float* wj = (const float*)d_in[3];
    const float* wk = (const float*)d_in[4];
    const float* ur = (const float*)d_in[5];
    const float* ui = (const float*)d_in[6];
    const float* uj = (const float*)d_in[7];
    const float* uk = (const float*)d_in[8];
    const float* bias = (const float*)d_in[9];
    float* out = (float*)d_out;

    char* ws = (char*)d_ws;
    f16* WhT  = (f16*)(ws);                          // 2 MB
    f16* UhT  = (f16*)(ws + (1 << 21));              // 2 MB
    unsigned int* hbuf = (unsigned int*)(ws + (1 << 22));      // 2 x 64 KB
    int* flags = (int*)(ws + (1 << 22) + (1 << 17)); // 32768 ints

    hipLaunchKernelGGL(qrnn_prep, dim3(8320), dim3(256), 0, stream,
                       wr, wi, wj, wk, ur, ui, uj, uk, WhT, UhT, flags);
    hipLaunchKernelGGL(qrnn_gemm, dim3(8, 128), dim3(256), 0, stream,
                       x, WhT, bias, out);
    hipLaunchKernelGGL(qrnn_scan, dim3(64), dim3(128), 0, stream,
                       UhT, hbuf, flags, out);
}